// Round 1
// baseline (1727.318 us; speedup 1.0000x reference)
//
#include <hip/hip_runtime.h>
#include <cstddef>

// ---------------------------------------------------------------------------
// MT_RNN round 6: rnn_serial de-LDS-ification.
// ws = two 128MB fp16 ping-pong halves (bufA/bufB), no aliasing:
//   1) bufA = tanh(x Wx0^T + bx0)            fp32 in  -> fp16 [M,256]
//   2) bufB = tanh(bufA Wx1^T + bx1)         fp16     -> fp16 [M,256]
//   3) bufA = bufB Wih^T + bih               fp16     -> fp16 zx [T,B,H]
//   4) serial: bufA (zx) -> bufB (h_all fp16 [T,B,H]), 16 CUs
//   5) bufA = tanh(bufB Wh0^T + bh0)         fp16     -> fp16 [M,256]
//   6) bufB = tanh(bufA Wh1^T + bh1)         fp16     -> fp16 [M,256]
//   7) out  = bufB Wg^T + bg                 fp16     -> fp32 [M,64]
//
// Round-6 change (rnn_serial only): old structure was 16 waves x 16 cols,
// every wave re-reading the whole 16x256 h tile -> 128 ds_read_b128/step/CU
// = 128KB at ~85B/cyc ~= 1540 of the 2256 cyc/step (LDS-pipe-bound).
// New: 4 waves x 64 cols, OPERANDS SWAPPED: A = Whh fragments (regs),
// B = h from LDS (one b128 per k-chunk shared across the wave's 4 j-tiles)
// -> 32 reads/step/CU. D maps to z[b=l15][j=4*quad+rg]: lane outputs
// contiguous in j -> ds_write_b64 x4 and packed 8B h_all stores.
// zx consumed as [T,B,H] so gemm step 3 writes plain row-major (no ZXT).
// ---------------------------------------------------------------------------

typedef _Float16 halfx8 __attribute__((ext_vector_type(8)));
typedef _Float16 halfx4 __attribute__((ext_vector_type(4)));
typedef float    f32x4  __attribute__((ext_vector_type(4)));

#define T_LEN 1024
#define B_SZ  256
#define H_DIM 256
#define M_ROWS (T_LEN * B_SZ)  // 262144

__device__ __forceinline__ float fast_tanh(float x) {
  float e = __expf(2.0f * x);
  return 1.0f - 2.0f / (e + 1.0f);
}

// sorted alpha assignment over 256 units: 86 x 0.001, 85 x 0.01, 85 x 0.1
__device__ __forceinline__ float alpha_of(int j) {
  return (j < 86) ? 0.001f : ((j < 171) ? 0.01f : 0.1f);
}

// barrier with LDS-only drain: global loads/stores stay in flight across it
__device__ __forceinline__ void lds_barrier() {
  asm volatile("s_waitcnt lgkmcnt(0)\n\ts_barrier" ::: "memory");
}

// ---------------------------------------------------------------------------
// fp16 MFMA GEMM, 8 waves, N=256, M-tile=32, grid-stride. W register-resident.
// INF32: A is fp32 (step 1 only), else fp16. ZXT: write transposed [T,H,B]
// (unused as of round 6, kept for reference).
// MFMA 16x16x32 layouts (HW-verified rounds 2-4):
//   A: A[m=lane&15][k=8*(lane>>4)+i]   B: B[k=8*(lane>>4)+i][n=lane&15]
//   D: col n=lane&15, row m=4*(lane>>4)+reg
// ---------------------------------------------------------------------------
template <int KCH, bool TANH, bool INF32, bool ZXT>
__global__ __launch_bounds__(512, 2)
void gemm8(const void* __restrict__ Ap, const float* __restrict__ W,
           const float* __restrict__ bias, void* __restrict__ Cp, int mtiles) {
  constexpr int K  = KCH * 32;
  constexpr int KP = K + 8;
  __shared__ __attribute__((aligned(16))) _Float16 Ah[32][KP];

  const int tid  = threadIdx.x;
  const int lane = tid & 63;
  const int wave = tid >> 6;   // 0..7, owns 32 output columns
  const int l15  = lane & 15;
  const int quad = lane >> 4;
  const int jw   = wave * 32;

  // register-resident W fragments (fp16)
  halfx8 Bf[2][KCH];
  float  bcol[2];
  int    jj[2];
#pragma unroll
  for (int nt = 0; nt < 2; nt++) {
    jj[nt]   = jw + nt * 16 + l15;
    bcol[nt] = bias[jj[nt]];
#pragma unroll
    for (int ks = 0; ks < KCH; ks++) {
      const float* wp = W + (size_t)jj[nt] * K + ks * 32 + quad * 8;
      float4 w0 = *(const float4*)wp;
      float4 w1 = *(const float4*)(wp + 4);
      halfx8 f;
      f[0] = (_Float16)w0.x; f[1] = (_Float16)w0.y;
      f[2] = (_Float16)w0.z; f[3] = (_Float16)w0.w;
      f[4] = (_Float16)w1.x; f[5] = (_Float16)w1.y;
      f[6] = (_Float16)w1.z; f[7] = (_Float16)w1.w;
      Bf[nt][ks] = f;
    }
  }

  const int srow = tid >> 4;   // 0..31 (16 threads per row)
  const int sk4  = tid & 15;

  for (int bm = blockIdx.x; bm < mtiles; bm += gridDim.x) {
    // ---- stage A tile (32 x K) into LDS as fp16 ----
    if constexpr (INF32) {
      const float* A = (const float*)Ap + (size_t)bm * 32 * K;
      constexpr int SEG = K / 64;
      float4 tv[SEG];
#pragma unroll
      for (int s = 0; s < SEG; s++)
        tv[s] = *(const float4*)(A + (size_t)srow * K + (sk4 + s * 16) * 4);
#pragma unroll
      for (int s = 0; s < SEG; s++) {
        halfx4 h;
        h[0] = (_Float16)tv[s].x; h[1] = (_Float16)tv[s].y;
        h[2] = (_Float16)tv[s].z; h[3] = (_Float16)tv[s].w;
        *(halfx4*)&Ah[srow][(sk4 + s * 16) * 4] = h;
      }
    } else {
      const _Float16* A = (const _Float16*)Ap + (size_t)bm * 32 * K;
      constexpr int SEG = K / 128;  // halfx8 loads per thread
      halfx8 tv[SEG];
#pragma unroll
      for (int s = 0; s < SEG; s++)
        tv[s] = *(const halfx8*)(A + (size_t)srow * K + (sk4 + s * 16) * 8);
#pragma unroll
      for (int s = 0; s < SEG; s++)
        *(halfx8*)&Ah[srow][(sk4 + s * 16) * 8] = tv[s];
    }
    lds_barrier();

    f32x4 acc[2][2];
#pragma unroll
    for (int mi = 0; mi < 2; mi++)
#pragma unroll
      for (int nt = 0; nt < 2; nt++) acc[mi][nt] = (f32x4){0.f, 0.f, 0.f, 0.f};

#pragma unroll
    for (int ks = 0; ks < KCH; ks++)
#pragma unroll
      for (int mi = 0; mi < 2; mi++) {
        halfx8 a = *(const halfx8*)&Ah[mi * 16 + l15][ks * 32 + quad * 8];
#pragma unroll
        for (int nt = 0; nt < 2; nt++)
          acc[mi][nt] = __builtin_amdgcn_mfma_f32_16x16x32_f16(a, Bf[nt][ks], acc[mi][nt], 0, 0, 0);
      }

    // ---- epilogue ----
    if constexpr (ZXT) {
      // zxT[t][j][b]: t = bm>>3, b = (bm&7)*32 + mi*16 + quad*4 + rg
      _Float16* C = (_Float16*)Cp;
      const size_t tb = (size_t)(bm >> 3) * (H_DIM * B_SZ) + (bm & 7) * 32 + quad * 4;
#pragma unroll
      for (int mi = 0; mi < 2; mi++)
#pragma unroll
        for (int nt = 0; nt < 2; nt++) {
          halfx4 o;
#pragma unroll
          for (int rg = 0; rg < 4; rg++)
            o[rg] = (_Float16)(acc[mi][nt][rg] + bcol[nt]);
          *(halfx4*)(C + tb + (size_t)jj[nt] * B_SZ + mi * 16) = o;
        }
    } else {
      _Float16* C = (_Float16*)Cp;
#pragma unroll
      for (int mi = 0; mi < 2; mi++)
#pragma unroll
        for (int nt = 0; nt < 2; nt++)
#pragma unroll
          for (int rg = 0; rg < 4; rg++) {
            const int rowg = bm * 32 + mi * 16 + quad * 4 + rg;
            float v = acc[mi][nt][rg] + bcol[nt];
            if (TANH) v = fast_tanh(v);
            C[(size_t)rowg * 256 + jj[nt]] = (_Float16)v;
          }
    }
    lds_barrier();  // MFMA reads done before next tile's staging writes
  }
}

// ---------------------------------------------------------------------------
// Final projection: out[M,64] fp32 = A[M,256] fp16 @ Wg^T + bg. 4 waves.
// ---------------------------------------------------------------------------
__global__ __launch_bounds__(256, 2)
void gemm4_out(const _Float16* __restrict__ A, const float* __restrict__ W,
               const float* __restrict__ bias, float* __restrict__ C,
               int mtiles) {
  constexpr int K = 256, KCH = 8, KP = 264;
  __shared__ __attribute__((aligned(16))) _Float16 Ah[32][KP];

  const int tid  = threadIdx.x;
  const int lane = tid & 63;
  const int wave = tid >> 6;   // 0..3
  const int l15  = lane & 15;
  const int quad = lane >> 4;
  const int jcol = wave * 16 + l15;

  halfx8 Bf[KCH];
  const float bc = bias[jcol];
#pragma unroll
  for (int ks = 0; ks < KCH; ks++) {
    const float* wp = W + (size_t)jcol * K + ks * 32 + quad * 8;
    float4 w0 = *(const float4*)wp;
    float4 w1 = *(const float4*)(wp + 4);
    halfx8 f;
    f[0] = (_Float16)w0.x; f[1] = (_Float16)w0.y;
    f[2] = (_Float16)w0.z; f[3] = (_Float16)w0.w;
    f[4] = (_Float16)w1.x; f[5] = (_Float16)w1.y;
    f[6] = (_Float16)w1.z; f[7] = (_Float16)w1.w;
    Bf[ks] = f;
  }

  const int srow = tid >> 3;  // 0..31, 8 thr/row
  const int sk   = tid & 7;

  for (int bm = blockIdx.x; bm < mtiles; bm += gridDim.x) {
    const _Float16* Ab = A + (size_t)bm * 32 * K;
    halfx8 tv[4];
#pragma unroll
    for (int s = 0; s < 4; s++)
      tv[s] = *(const halfx8*)(Ab + (size_t)srow * K + (sk + s * 8) * 8);
#pragma unroll
    for (int s = 0; s < 4; s++)
      *(halfx8*)&Ah[srow][(sk + s * 8) * 8] = tv[s];
    lds_barrier();

    f32x4 acc[2];
#pragma unroll
    for (int mi = 0; mi < 2; mi++) acc[mi] = (f32x4){0.f, 0.f, 0.f, 0.f};
#pragma unroll
    for (int ks = 0; ks < KCH; ks++)
#pragma unroll
      for (int mi = 0; mi < 2; mi++) {
        halfx8 a = *(const halfx8*)&Ah[mi * 16 + l15][ks * 32 + quad * 8];
        acc[mi] = __builtin_amdgcn_mfma_f32_16x16x32_f16(a, Bf[ks], acc[mi], 0, 0, 0);
      }

#pragma unroll
    for (int mi = 0; mi < 2; mi++)
#pragma unroll
      for (int rg = 0; rg < 4; rg++) {
        const int rowg = bm * 32 + mi * 16 + quad * 4 + rg;
        C[(size_t)rowg * 64 + jcol] = acc[mi][rg] + bc;
      }
    lds_barrier();
  }
}

// ---------------------------------------------------------------------------
// Serial recurrence, round 6: 16 blocks x 256 threads (4 waves, 1/SIMD).
// Block owns 16 batch rows; wave owns 64 h-columns (4 j-tiles).
// OPERANDS SWAPPED vs round 5: A = Whh fragments (register-resident,
// A[m=j][k]); B = h from LDS (B[k][n=b]); one ds_read_b128 per k-chunk
// feeds 4 MFMAs -> 32 reads/step/CU (was 128). D: lane(l15,quad) holds
// z[b=r0+l15][j=jb+mt*16+4*quad+rg] -> j-contiguous in rg: LDS publish is
// 4 x ds_write_b64 (2-way bank alias only = free) and h_all store is
// 4 x 8B packed. zx is [T,B,H] (plain row-major from gemm step 3).
// zx prefetched 2 steps ahead; tail overruns 256KB into bufB (in-bounds,
// discarded). One lgkm-only barrier per step; t-loop unrolled x2 so the
// LDS double-buffer index is static.
// ---------------------------------------------------------------------------
__global__ __launch_bounds__(256, 1)
void rnn_serial(const _Float16* __restrict__ zx,   // [T,B,H]
                _Float16* __restrict__ h_all,      // [T,B,H]
                const float* __restrict__ Whh,     // [H,H]
                const float* __restrict__ bhh_p)   // [H]
{
  __shared__ __attribute__((aligned(16))) _Float16 hB[2][16][264];

  const int tid  = threadIdx.x;
  const int lane = tid & 63;
  const int wave = tid >> 6;   // 0..3, owns 64 h-columns
  const int l15  = lane & 15;  // batch row (n of D) / Whh-row select (m of A)
  const int quad = lane >> 4;
  const int r0   = blockIdx.x * 16;
  const int jb   = wave * 64;

  // A-fragments: Whh rows j = jb + mt*16 + l15, A[m=l15][k=8*quad+i]
  halfx8 Af[4][8];
#pragma unroll
  for (int mt = 0; mt < 4; mt++) {
    const int j = jb + mt * 16 + l15;
#pragma unroll
    for (int ks = 0; ks < 8; ks++) {
      const float* wp = Whh + (size_t)j * H_DIM + ks * 32 + quad * 8;
      float4 w0 = *(const float4*)wp;
      float4 w1 = *(const float4*)(wp + 4);
      halfx8 f;
      f[0] = (_Float16)w0.x; f[1] = (_Float16)w0.y;
      f[2] = (_Float16)w0.z; f[3] = (_Float16)w0.w;
      f[4] = (_Float16)w1.x; f[5] = (_Float16)w1.y;
      f[6] = (_Float16)w1.z; f[7] = (_Float16)w1.w;
      Af[mt][ks] = f;
    }
  }

  // per-output constants: j = jb + mt*16 + quad*4 + rg
  float bj[4][4], aj[4][4], oma[4][4];
#pragma unroll
  for (int mt = 0; mt < 4; mt++)
#pragma unroll
    for (int rg = 0; rg < 4; rg++) {
      const int j = jb + mt * 16 + quad * 4 + rg;
      bj[mt][rg]  = bhh_p[j];
      aj[mt][rg]  = alpha_of(j);
      oma[mt][rg] = 1.0f - aj[mt][rg];
    }

  // init h buffer 0 = 0
  for (int i = tid; i < 16 * 264; i += 256) (&hB[0][0][0])[i] = (_Float16)0.0f;
  __syncthreads();

  // precomputed LDS pointers (double-buffered)
  // read: B-fragment h[b=l15][k = ks*32 + quad*8 + i]
  const _Float16* rdp[2] = {&hB[0][l15][quad * 8], &hB[1][l15][quad * 8]};
  // write: h_new[b=l15][j = jb + mt*16 + quad*4 + rg] (rg contiguous -> b64)
  _Float16*       wrp[2] = {&hB[1][l15][jb + quad * 4], &hB[0][l15][jb + quad * 4]};

  constexpr int STRIDE = B_SZ * H_DIM;  // 65536 elements per t
  const _Float16* zp = zx    + (size_t)(r0 + l15) * H_DIM + jb + quad * 4;
  _Float16*       hp = h_all + (size_t)(r0 + l15) * H_DIM + jb + quad * 4;

  // zx pipeline: zc = fp32 zx[t] for current step; zA = raw zx[t+1]
  float  zc[4][4];
  halfx4 zA[4];
  {
#pragma unroll
    for (int mt = 0; mt < 4; mt++) {
      halfx4 z0 = *(const halfx4*)(zp + mt * 16);
      zA[mt]    = *(const halfx4*)(zp + mt * 16 + STRIDE);
#pragma unroll
      for (int rg = 0; rg < 4; rg++) zc[mt][rg] = (float)z0[rg];
    }
    zp += 2 * (size_t)STRIDE;
  }

  // h state: fp32 + its published fp16 image (packed per j-tile)
  float  hreg[4][4];
  halfx4 hh4[4];
#pragma unroll
  for (int mt = 0; mt < 4; mt++) {
#pragma unroll
    for (int rg = 0; rg < 4; rg++) {
      hreg[mt][rg] = 0.0f;
      hh4[mt][rg]  = (_Float16)0.0f;
    }
  }

  auto step = [&](int p) {
    // prefetch zx two steps ahead (4 x 8B, offsets are 32B immediates)
    halfx4 znew[4];
#pragma unroll
    for (int mt = 0; mt < 4; mt++) znew[mt] = *(const halfx4*)(zp + mt * 16);
    zp += STRIDE;

    // B-fragments: 8 x ds_read_b128, each shared across the 4 j-tiles
    const _Float16* rd = rdp[p];
    halfx8 hb[8];
#pragma unroll
    for (int ks = 0; ks < 8; ks++) hb[ks] = *(const halfx8*)(rd + ks * 32);

    f32x4 acc[4];
#pragma unroll
    for (int mt = 0; mt < 4; mt++) acc[mt] = (f32x4){0.f, 0.f, 0.f, 0.f};
#pragma unroll
    for (int ks = 0; ks < 8; ks++)
#pragma unroll
      for (int mt = 0; mt < 4; mt++)
        acc[mt] = __builtin_amdgcn_mfma_f32_16x16x32_f16(Af[mt][ks], hb[ks], acc[mt], 0, 0, 0);

    // epilogue: tanh + alpha-blend; publish packed halfx4 per j-tile
    _Float16* wr = wrp[p];
#pragma unroll
    for (int mt = 0; mt < 4; mt++) {
      halfx4 hnew;
#pragma unroll
      for (int rg = 0; rg < 4; rg++) {
        float hr = fast_tanh(zc[mt][rg] + acc[mt][rg] + bj[mt][rg]);
        float hn = oma[mt][rg] * hreg[mt][rg] + aj[mt][rg] * hr;
        hreg[mt][rg] = hn;
        hnew[rg] = (_Float16)hn;
      }
      *(halfx4*)(hp + mt * 16) = hh4[mt];   // h_all[t] = pre-update h_t
      hh4[mt] = hnew;
      *(halfx4*)(wr + mt * 16) = hnew;      // next step's B operand (b64)
    }
    hp += STRIDE;

    lds_barrier();  // lgkm-only: global loads/stores stay in flight

    // shift zx pipeline
#pragma unroll
    for (int mt = 0; mt < 4; mt++) {
#pragma unroll
      for (int rg = 0; rg < 4; rg++) zc[mt][rg] = (float)zA[mt][rg];
      zA[mt] = znew[mt];
    }
  };

  for (int it = 0; it < T_LEN / 2; ++it) {
    step(0);
    step(1);
  }
}

// ---------------------------------------------------------------------------
extern "C" void kernel_launch(void* const* d_in, const int* in_sizes, int n_in,
                              void* d_out, int out_size, void* d_ws, size_t ws_size,
                              hipStream_t stream) {
  const float* x   = (const float*)d_in[0];
  const float* Wx0 = (const float*)d_in[1];
  const float* bx0 = (const float*)d_in[2];
  const float* Wx1 = (const float*)d_in[3];
  const float* bx1 = (const float*)d_in[4];
  const float* Wih = (const float*)d_in[5];
  const float* Whh = (const float*)d_in[6];
  const float* bih = (const float*)d_in[7];
  const float* bhh = (const float*)d_in[8];
  const float* Wh0 = (const float*)d_in[9];
  const float* bh0 = (const float*)d_in[10];
  const float* Wh1 = (const float*)d_in[11];
  const float* bh1 = (const float*)d_in[12];
  const float* Wg  = (const float*)d_in[13];
  const float* bg  = (const float*)d_in[14];
  float* out = (float*)d_out;

  // two fp16 ping-pong halves, 128 MB each (ws >= 256 MB)
  _Float16* bufA = (_Float16*)d_ws;
  _Float16* bufB = bufA + (size_t)M_ROWS * 256;

  const int MT = M_ROWS / 32;  // 8192 m-tiles

  // 1) bufA = tanh(x Wx0^T + bx0)            fp32 -> fp16
  gemm8<2, true, true, false><<<512, 512, 0, stream>>>(x, Wx0, bx0, bufA, MT);
  // 2) bufB = tanh(bufA Wx1^T + bx1)
  gemm8<8, true, false, false><<<512, 512, 0, stream>>>(bufA, Wx1, bx1, bufB, MT);
  // 3) bufA = bufB Wih^T + bih, plain row-major zx [T,B,H]
  gemm8<8, false, false, false><<<512, 512, 0, stream>>>(bufB, Wih, bih, bufA, MT);
  // 4) serial recurrence: zx (bufA) -> h_all (bufB)
  rnn_serial<<<16, 256, 0, stream>>>(bufA, bufB, Whh, bhh);
  // 5) bufA = tanh(bufB Wh0^T + bh0)
  gemm8<8, true, false, false><<<512, 512, 0, stream>>>(bufB, Wh0, bh0, bufA, MT);
  // 6) bufB = tanh(bufA Wh1^T + bh1)
  gemm8<8, true, false, false><<<512, 512, 0, stream>>>(bufA, Wh1, bh1, bufB, MT);
  // 7) out = bufB Wg^T + bg                  fp16 -> fp32
  gemm4_out<<<512, 256, 0, stream>>>(bufB, Wg, bg, out, MT);
}

// Round 2
// 1460.311 us; speedup vs baseline: 1.1828x; 1.1828x over previous
//
#include <hip/hip_runtime.h>
#include <cstddef>

// ---------------------------------------------------------------------------
// MT_RNN round 7: rnn_serial = round-6 swapped-operand structure, but with
// 8 waves (2/SIMD) instead of 4 (1/SIMD).
// Round-6 post-mortem: 4 waves cut LDS reads 128->32/step but killed TLP
// (1 wave/SIMD) -> latency-bound, step 2256->2937 cyc. Round 7 keeps the
// operand swap (Whh register-resident A, h as B, one ds_read_b128 shared
// across the wave's j-tiles) at 64 reads/step/CU with 2 waves/SIMD to hide
// ds_read/MFMA/VALU latencies. Expected step ~1000-1150 cyc.
//
// ws = two 128MB fp16 ping-pong halves (bufA/bufB), no aliasing:
//   1) bufA = tanh(x Wx0^T + bx0)            fp32 in  -> fp16 [M,256]
//   2) bufB = tanh(bufA Wx1^T + bx1)         fp16     -> fp16 [M,256]
//   3) bufA = bufB Wih^T + bih               fp16     -> fp16 zx [T,B,H]
//   4) serial: bufA (zx) -> bufB (h_all fp16 [T,B,H]), 16 CUs
//   5) bufA = tanh(bufB Wh0^T + bh0)         fp16     -> fp16 [M,256]
//   6) bufB = tanh(bufA Wh1^T + bh1)         fp16     -> fp16 [M,256]
//   7) out  = bufB Wg^T + bg                 fp16     -> fp32 [M,64]
// ---------------------------------------------------------------------------

typedef _Float16 halfx8 __attribute__((ext_vector_type(8)));
typedef _Float16 halfx4 __attribute__((ext_vector_type(4)));
typedef float    f32x4  __attribute__((ext_vector_type(4)));

#define T_LEN 1024
#define B_SZ  256
#define H_DIM 256
#define M_ROWS (T_LEN * B_SZ)  // 262144

__device__ __forceinline__ float fast_tanh(float x) {
  float e = __expf(2.0f * x);
  return 1.0f - 2.0f / (e + 1.0f);
}

// sorted alpha assignment over 256 units: 86 x 0.001, 85 x 0.01, 85 x 0.1
__device__ __forceinline__ float alpha_of(int j) {
  return (j < 86) ? 0.001f : ((j < 171) ? 0.01f : 0.1f);
}

// barrier with LDS-only drain: global loads/stores stay in flight across it
__device__ __forceinline__ void lds_barrier() {
  asm volatile("s_waitcnt lgkmcnt(0)\n\ts_barrier" ::: "memory");
}

// ---------------------------------------------------------------------------
// fp16 MFMA GEMM, 8 waves, N=256, M-tile=32, grid-stride. W register-resident.
// INF32: A is fp32 (step 1 only), else fp16. ZXT: write transposed [T,H,B]
// (unused as of round 6, kept for reference).
// MFMA 16x16x32 layouts (HW-verified rounds 2-4):
//   A: A[m=lane&15][k=8*(lane>>4)+i]   B: B[k=8*(lane>>4)+i][n=lane&15]
//   D: col n=lane&15, row m=4*(lane>>4)+reg
// ---------------------------------------------------------------------------
template <int KCH, bool TANH, bool INF32, bool ZXT>
__global__ __launch_bounds__(512, 2)
void gemm8(const void* __restrict__ Ap, const float* __restrict__ W,
           const float* __restrict__ bias, void* __restrict__ Cp, int mtiles) {
  constexpr int K  = KCH * 32;
  constexpr int KP = K + 8;
  __shared__ __attribute__((aligned(16))) _Float16 Ah[32][KP];

  const int tid  = threadIdx.x;
  const int lane = tid & 63;
  const int wave = tid >> 6;   // 0..7, owns 32 output columns
  const int l15  = lane & 15;
  const int quad = lane >> 4;
  const int jw   = wave * 32;

  // register-resident W fragments (fp16)
  halfx8 Bf[2][KCH];
  float  bcol[2];
  int    jj[2];
#pragma unroll
  for (int nt = 0; nt < 2; nt++) {
    jj[nt]   = jw + nt * 16 + l15;
    bcol[nt] = bias[jj[nt]];
#pragma unroll
    for (int ks = 0; ks < KCH; ks++) {
      const float* wp = W + (size_t)jj[nt] * K + ks * 32 + quad * 8;
      float4 w0 = *(const float4*)wp;
      float4 w1 = *(const float4*)(wp + 4);
      halfx8 f;
      f[0] = (_Float16)w0.x; f[1] = (_Float16)w0.y;
      f[2] = (_Float16)w0.z; f[3] = (_Float16)w0.w;
      f[4] = (_Float16)w1.x; f[5] = (_Float16)w1.y;
      f[6] = (_Float16)w1.z; f[7] = (_Float16)w1.w;
      Bf[nt][ks] = f;
    }
  }

  const int srow = tid >> 4;   // 0..31 (16 threads per row)
  const int sk4  = tid & 15;

  for (int bm = blockIdx.x; bm < mtiles; bm += gridDim.x) {
    // ---- stage A tile (32 x K) into LDS as fp16 ----
    if constexpr (INF32) {
      const float* A = (const float*)Ap + (size_t)bm * 32 * K;
      constexpr int SEG = K / 64;
      float4 tv[SEG];
#pragma unroll
      for (int s = 0; s < SEG; s++)
        tv[s] = *(const float4*)(A + (size_t)srow * K + (sk4 + s * 16) * 4);
#pragma unroll
      for (int s = 0; s < SEG; s++) {
        halfx4 h;
        h[0] = (_Float16)tv[s].x; h[1] = (_Float16)tv[s].y;
        h[2] = (_Float16)tv[s].z; h[3] = (_Float16)tv[s].w;
        *(halfx4*)&Ah[srow][(sk4 + s * 16) * 4] = h;
      }
    } else {
      const _Float16* A = (const _Float16*)Ap + (size_t)bm * 32 * K;
      constexpr int SEG = K / 128;  // halfx8 loads per thread
      halfx8 tv[SEG];
#pragma unroll
      for (int s = 0; s < SEG; s++)
        tv[s] = *(const halfx8*)(A + (size_t)srow * K + (sk4 + s * 16) * 8);
#pragma unroll
      for (int s = 0; s < SEG; s++)
        *(halfx8*)&Ah[srow][(sk4 + s * 16) * 8] = tv[s];
    }
    lds_barrier();

    f32x4 acc[2][2];
#pragma unroll
    for (int mi = 0; mi < 2; mi++)
#pragma unroll
      for (int nt = 0; nt < 2; nt++) acc[mi][nt] = (f32x4){0.f, 0.f, 0.f, 0.f};

#pragma unroll
    for (int ks = 0; ks < KCH; ks++)
#pragma unroll
      for (int mi = 0; mi < 2; mi++) {
        halfx8 a = *(const halfx8*)&Ah[mi * 16 + l15][ks * 32 + quad * 8];
#pragma unroll
        for (int nt = 0; nt < 2; nt++)
          acc[mi][nt] = __builtin_amdgcn_mfma_f32_16x16x32_f16(a, Bf[nt][ks], acc[mi][nt], 0, 0, 0);
      }

    // ---- epilogue ----
    if constexpr (ZXT) {
      // zxT[t][j][b]: t = bm>>3, b = (bm&7)*32 + mi*16 + quad*4 + rg
      _Float16* C = (_Float16*)Cp;
      const size_t tb = (size_t)(bm >> 3) * (H_DIM * B_SZ) + (bm & 7) * 32 + quad * 4;
#pragma unroll
      for (int mi = 0; mi < 2; mi++)
#pragma unroll
        for (int nt = 0; nt < 2; nt++) {
          halfx4 o;
#pragma unroll
          for (int rg = 0; rg < 4; rg++)
            o[rg] = (_Float16)(acc[mi][nt][rg] + bcol[nt]);
          *(halfx4*)(C + tb + (size_t)jj[nt] * B_SZ + mi * 16) = o;
        }
    } else {
      _Float16* C = (_Float16*)Cp;
#pragma unroll
      for (int mi = 0; mi < 2; mi++)
#pragma unroll
        for (int nt = 0; nt < 2; nt++)
#pragma unroll
          for (int rg = 0; rg < 4; rg++) {
            const int rowg = bm * 32 + mi * 16 + quad * 4 + rg;
            float v = acc[mi][nt][rg] + bcol[nt];
            if (TANH) v = fast_tanh(v);
            C[(size_t)rowg * 256 + jj[nt]] = (_Float16)v;
          }
    }
    lds_barrier();  // MFMA reads done before next tile's staging writes
  }
}

// ---------------------------------------------------------------------------
// Final projection: out[M,64] fp32 = A[M,256] fp16 @ Wg^T + bg. 4 waves.
// ---------------------------------------------------------------------------
__global__ __launch_bounds__(256, 2)
void gemm4_out(const _Float16* __restrict__ A, const float* __restrict__ W,
               const float* __restrict__ bias, float* __restrict__ C,
               int mtiles) {
  constexpr int K = 256, KCH = 8, KP = 264;
  __shared__ __attribute__((aligned(16))) _Float16 Ah[32][KP];

  const int tid  = threadIdx.x;
  const int lane = tid & 63;
  const int wave = tid >> 6;   // 0..3
  const int l15  = lane & 15;
  const int quad = lane >> 4;
  const int jcol = wave * 16 + l15;

  halfx8 Bf[KCH];
  const float bc = bias[jcol];
#pragma unroll
  for (int ks = 0; ks < KCH; ks++) {
    const float* wp = W + (size_t)jcol * K + ks * 32 + quad * 8;
    float4 w0 = *(const float4*)wp;
    float4 w1 = *(const float4*)(wp + 4);
    halfx8 f;
    f[0] = (_Float16)w0.x; f[1] = (_Float16)w0.y;
    f[2] = (_Float16)w0.z; f[3] = (_Float16)w0.w;
    f[4] = (_Float16)w1.x; f[5] = (_Float16)w1.y;
    f[6] = (_Float16)w1.z; f[7] = (_Float16)w1.w;
    Bf[ks] = f;
  }

  const int srow = tid >> 3;  // 0..31, 8 thr/row
  const int sk   = tid & 7;

  for (int bm = blockIdx.x; bm < mtiles; bm += gridDim.x) {
    const _Float16* Ab = A + (size_t)bm * 32 * K;
    halfx8 tv[4];
#pragma unroll
    for (int s = 0; s < 4; s++)
      tv[s] = *(const halfx8*)(Ab + (size_t)srow * K + (sk + s * 8) * 8);
#pragma unroll
    for (int s = 0; s < 4; s++)
      *(halfx8*)&Ah[srow][(sk + s * 8) * 8] = tv[s];
    lds_barrier();

    f32x4 acc[2];
#pragma unroll
    for (int mi = 0; mi < 2; mi++) acc[mi] = (f32x4){0.f, 0.f, 0.f, 0.f};
#pragma unroll
    for (int ks = 0; ks < KCH; ks++)
#pragma unroll
      for (int mi = 0; mi < 2; mi++) {
        halfx8 a = *(const halfx8*)&Ah[mi * 16 + l15][ks * 32 + quad * 8];
        acc[mi] = __builtin_amdgcn_mfma_f32_16x16x32_f16(a, Bf[ks], acc[mi], 0, 0, 0);
      }

#pragma unroll
    for (int mi = 0; mi < 2; mi++)
#pragma unroll
      for (int rg = 0; rg < 4; rg++) {
        const int rowg = bm * 32 + mi * 16 + quad * 4 + rg;
        C[(size_t)rowg * 64 + jcol] = acc[mi][rg] + bc;
      }
    lds_barrier();
  }
}

// ---------------------------------------------------------------------------
// Serial recurrence, round 7: 16 blocks x 512 threads (8 waves, 2/SIMD).
// Block owns 16 batch rows; wave owns 32 h-columns (2 j-tiles).
// A = Whh fragments (register-resident, A[m=j][k]); B = h from LDS
// (B[k][n=b]); one ds_read_b128 per k-chunk feeds the wave's 2 j-tiles
// -> 64 reads/step/CU (round 5: 128, round 6: 32-but-latency-bound).
// D: lane(l15,quad) holds z[b=r0+l15][j=jb+mt*16+4*quad+rg] -> j-contiguous
// in rg: LDS publish is 2 x ds_write_b64 (2-way bank alias = free) and
// h_all store is 2 x 8B packed. zx is [T,B,H] (row-major from gemm 3).
// zx prefetched 2 steps ahead; tail overruns 256KB into bufB (in-bounds,
// discarded). One lgkm-only barrier per step; t-loop unrolled x2 so the
// LDS double-buffer index is static.
// ---------------------------------------------------------------------------
__global__ __launch_bounds__(512, 2)
void rnn_serial(const _Float16* __restrict__ zx,   // [T,B,H]
                _Float16* __restrict__ h_all,      // [T,B,H]
                const float* __restrict__ Whh,     // [H,H]
                const float* __restrict__ bhh_p)   // [H]
{
  __shared__ __attribute__((aligned(16))) _Float16 hB[2][16][264];

  const int tid  = threadIdx.x;
  const int lane = tid & 63;
  const int wave = tid >> 6;   // 0..7, owns 32 h-columns
  const int l15  = lane & 15;  // batch row (n of D) / Whh-row select (m of A)
  const int quad = lane >> 4;
  const int r0   = blockIdx.x * 16;
  const int jb   = wave * 32;

  // A-fragments: Whh rows j = jb + mt*16 + l15, A[m=l15][k=8*quad+i]
  halfx8 Af[2][8];
#pragma unroll
  for (int mt = 0; mt < 2; mt++) {
    const int j = jb + mt * 16 + l15;
#pragma unroll
    for (int ks = 0; ks < 8; ks++) {
      const float* wp = Whh + (size_t)j * H_DIM + ks * 32 + quad * 8;
      float4 w0 = *(const float4*)wp;
      float4 w1 = *(const float4*)(wp + 4);
      halfx8 f;
      f[0] = (_Float16)w0.x; f[1] = (_Float16)w0.y;
      f[2] = (_Float16)w0.z; f[3] = (_Float16)w0.w;
      f[4] = (_Float16)w1.x; f[5] = (_Float16)w1.y;
      f[6] = (_Float16)w1.z; f[7] = (_Float16)w1.w;
      Af[mt][ks] = f;
    }
  }

  // per-output constants: j = jb + mt*16 + quad*4 + rg
  float bj[2][4], aj[2][4], oma[2][4];
#pragma unroll
  for (int mt = 0; mt < 2; mt++)
#pragma unroll
    for (int rg = 0; rg < 4; rg++) {
      const int j = jb + mt * 16 + quad * 4 + rg;
      bj[mt][rg]  = bhh_p[j];
      aj[mt][rg]  = alpha_of(j);
      oma[mt][rg] = 1.0f - aj[mt][rg];
    }

  // init h buffer 0 = 0
  for (int i = tid; i < 16 * 264; i += 512) (&hB[0][0][0])[i] = (_Float16)0.0f;
  __syncthreads();

  // precomputed LDS pointers (double-buffered)
  // read: B-fragment h[b=l15][k = ks*32 + quad*8 + i] (same addrs all waves)
  const _Float16* rdp[2] = {&hB[0][l15][quad * 8], &hB[1][l15][quad * 8]};
  // write: h_new[b=l15][j = jb + mt*16 + quad*4 + rg] (rg contiguous -> b64)
  _Float16*       wrp[2] = {&hB[1][l15][jb + quad * 4], &hB[0][l15][jb + quad * 4]};

  constexpr int STRIDE = B_SZ * H_DIM;  // 65536 elements per t
  const _Float16* zp = zx    + (size_t)(r0 + l15) * H_DIM + jb + quad * 4;
  _Float16*       hp = h_all + (size_t)(r0 + l15) * H_DIM + jb + quad * 4;

  // zx pipeline: zc = fp32 zx[t] for current step; zA = raw zx[t+1]
  float  zc[2][4];
  halfx4 zA[2];
  {
#pragma unroll
    for (int mt = 0; mt < 2; mt++) {
      halfx4 z0 = *(const halfx4*)(zp + mt * 16);
      zA[mt]    = *(const halfx4*)(zp + mt * 16 + STRIDE);
#pragma unroll
      for (int rg = 0; rg < 4; rg++) zc[mt][rg] = (float)z0[rg];
    }
    zp += 2 * (size_t)STRIDE;
  }

  // h state: fp32 + its published fp16 image (packed per j-tile)
  float  hreg[2][4];
  halfx4 hh4[2];
#pragma unroll
  for (int mt = 0; mt < 2; mt++) {
#pragma unroll
    for (int rg = 0; rg < 4; rg++) {
      hreg[mt][rg] = 0.0f;
      hh4[mt][rg]  = (_Float16)0.0f;
    }
  }

  auto step = [&](int p) {
    // prefetch zx two steps ahead (2 x 8B, offsets are 32B immediates)
    halfx4 znew[2];
#pragma unroll
    for (int mt = 0; mt < 2; mt++) znew[mt] = *(const halfx4*)(zp + mt * 16);
    zp += STRIDE;

    // B-fragments: 8 x ds_read_b128, each shared across the 2 j-tiles
    const _Float16* rd = rdp[p];
    halfx8 hb[8];
#pragma unroll
    for (int ks = 0; ks < 8; ks++) hb[ks] = *(const halfx8*)(rd + ks * 32);

    f32x4 acc[2];
#pragma unroll
    for (int mt = 0; mt < 2; mt++) acc[mt] = (f32x4){0.f, 0.f, 0.f, 0.f};
#pragma unroll
    for (int ks = 0; ks < 8; ks++)
#pragma unroll
      for (int mt = 0; mt < 2; mt++)
        acc[mt] = __builtin_amdgcn_mfma_f32_16x16x32_f16(Af[mt][ks], hb[ks], acc[mt], 0, 0, 0);

    // epilogue: tanh + alpha-blend; publish packed halfx4 per j-tile
    _Float16* wr = wrp[p];
#pragma unroll
    for (int mt = 0; mt < 2; mt++) {
      halfx4 hnew;
#pragma unroll
      for (int rg = 0; rg < 4; rg++) {
        float hr = fast_tanh(zc[mt][rg] + acc[mt][rg] + bj[mt][rg]);
        float hn = oma[mt][rg] * hreg[mt][rg] + aj[mt][rg] * hr;
        hreg[mt][rg] = hn;
        hnew[rg] = (_Float16)hn;
      }
      *(halfx4*)(hp + mt * 16) = hh4[mt];   // h_all[t] = pre-update h_t
      hh4[mt] = hnew;
      *(halfx4*)(wr + mt * 16) = hnew;      // next step's B operand (b64)
    }
    hp += STRIDE;

    lds_barrier();  // lgkm-only: global loads/stores stay in flight

    // shift zx pipeline
#pragma unroll
    for (int mt = 0; mt < 2; mt++) {
#pragma unroll
      for (int rg = 0; rg < 4; rg++) zc[mt][rg] = (float)zA[mt][rg];
      zA[mt] = znew[mt];
    }
  };

  for (int it = 0; it < T_LEN / 2; ++it) {
    step(0);
    step(1);
  }
}

// ---------------------------------------------------------------------------
extern "C" void kernel_launch(void* const* d_in, const int* in_sizes, int n_in,
                              void* d_out, int out_size, void* d_ws, size_t ws_size,
                              hipStream_t stream) {
  const float* x   = (const float*)d_in[0];
  const float* Wx0 = (const float*)d_in[1];
  const float* bx0 = (const float*)d_in[2];
  const float* Wx1 = (const float*)d_in[3];
  const float* bx1 = (const float*)d_in[4];
  const float* Wih = (const float*)d_in[5];
  const float* Whh = (const float*)d_in[6];
  const float* bih = (const float*)d_in[7];
  const float* bhh = (const float*)d_in[8];
  const float* Wh0 = (const float*)d_in[9];
  const float* bh0 = (const float*)d_in[10];
  const float* Wh1 = (const float*)d_in[11];
  const float* bh1 = (const float*)d_in[12];
  const float* Wg  = (const float*)d_in[13];
  const float* bg  = (const float*)d_in[14];
  float* out = (float*)d_out;

  // two fp16 ping-pong halves, 128 MB each (ws >= 256 MB)
  _Float16* bufA = (_Float16*)d_ws;
  _Float16* bufB = bufA + (size_t)M_ROWS * 256;

  const int MT = M_ROWS / 32;  // 8192 m-tiles

  // 1) bufA = tanh(x Wx0^T + bx0)            fp32 -> fp16
  gemm8<2, true, true, false><<<512, 512, 0, stream>>>(x, Wx0, bx0, bufA, MT);
  // 2) bufB = tanh(bufA Wx1^T + bx1)
  gemm8<8, true, false, false><<<512, 512, 0, stream>>>(bufA, Wx1, bx1, bufB, MT);
  // 3) bufA = bufB Wih^T + bih, plain row-major zx [T,B,H]
  gemm8<8, false, false, false><<<512, 512, 0, stream>>>(bufB, Wih, bih, bufA, MT);
  // 4) serial recurrence: zx (bufA) -> h_all (bufB)
  rnn_serial<<<16, 512, 0, stream>>>(bufA, bufB, Whh, bhh);
  // 5) bufA = tanh(bufB Wh0^T + bh0)
  gemm8<8, true, false, false><<<512, 512, 0, stream>>>(bufB, Wh0, bh0, bufA, MT);
  // 6) bufB = tanh(bufA Wh1^T + bh1)
  gemm8<8, true, false, false><<<512, 512, 0, stream>>>(bufA, Wh1, bh1, bufB, MT);
  // 7) out = bufB Wg^T + bg                  fp16 -> fp32
  gemm4_out<<<512, 256, 0, stream>>>(bufB, Wg, bg, out, MT);
}